// Round 7
// baseline (425.278 us; speedup 1.0000x reference)
//
#include <hip/hip_runtime.h>

#define N_NODES 50000
#define N_EDGES 800000
#define FDIM 64
#define NST 50000   // PT row stride (floats)
#define SA_BLOCKS ((N_NODES + 1023) / 1024)

// ---------------- edge weight + CSR construction ----------------

__global__ __launch_bounds__(256) void hist_kernel(const int* __restrict__ row,
                                                   int* __restrict__ cnt, int E) {
  int e = blockIdx.x * 256 + threadIdx.x;
  if (e < E) atomicAdd(&cnt[row[e]], 1);
}

// hierarchical scan: A) per-1024 block scan, B) scan block sums, C) apply
__global__ __launch_bounds__(1024) void scanA_kernel(const int* __restrict__ cnt,
                                                     int* __restrict__ offs,
                                                     int* __restrict__ bsum,
                                                     int n) {
  __shared__ int s[1024];
  int t = threadIdx.x;
  int i = blockIdx.x * 1024 + t;
  int v = (i < n) ? cnt[i] : 0;
  s[t] = v;
  __syncthreads();
  for (int d = 1; d < 1024; d <<= 1) {
    int add = (t >= d) ? s[t - d] : 0;
    __syncthreads();
    s[t] += add;
    __syncthreads();
  }
  if (i < n) offs[i] = s[t] - v;  // local exclusive
  if (t == 1023) bsum[blockIdx.x] = s[1023];
}

__global__ __launch_bounds__(64) void scanB_kernel(int* __restrict__ bsum,
                                                   int* __restrict__ boff,
                                                   int nb) {
  __shared__ int s[64];
  int t = threadIdx.x;
  int v = (t < nb) ? bsum[t] : 0;
  s[t] = v;
  __syncthreads();
  for (int d = 1; d < 64; d <<= 1) {
    int add = (t >= d) ? s[t - d] : 0;
    __syncthreads();
    s[t] += add;
    __syncthreads();
  }
  if (t < nb) boff[t] = s[t] - v;  // exclusive
}

__global__ __launch_bounds__(1024) void scanC_kernel(int* __restrict__ offs,
                                                     int* __restrict__ cursor,
                                                     const int* __restrict__ boff,
                                                     int n, int E) {
  int t = threadIdx.x;
  int i = blockIdx.x * 1024 + t;
  int bo = boff[blockIdx.x];
  if (i < n) {
    int o = offs[i] + bo;
    offs[i] = o;
    cursor[i] = o;
  }
  if (i == 0) offs[n] = E;
}

__global__ __launch_bounds__(256) void scatter_kernel(
    const int* __restrict__ row, const int* __restrict__ col,
    const float* __restrict__ ent, const float* __restrict__ ccf,
    const float* __restrict__ wsym, const float* __restrict__ encw,
    const float* __restrict__ encb, const float* __restrict__ q,
    int* __restrict__ cursor, int* __restrict__ col_s,
    float2* __restrict__ ws, int E) {
  int e = blockIdx.x * 256 + threadIdx.x;
  if (e >= E) return;
  float se = encw[0] * ent[e] + encw[1] * ccf[e] + encb[0];
  float ph = q[0] * se;
  float sw, cw;
  sincosf(ph, &sw, &cw);
  float w = wsym[e];
  int pos = atomicAdd(&cursor[row[e]], 1);
  col_s[pos] = col[e];
  ws[pos] = make_float2(w * cw, w * sw);
}

// ---------------- weight transpose prep ----------------

__global__ __launch_bounds__(256) void prep_weights(
    const float* __restrict__ r0, const float* __restrict__ i0,
    const float* __restrict__ r1, const float* __restrict__ i1,
    float* __restrict__ r0T, float* __restrict__ i0T, float* __restrict__ r1T,
    float* __restrict__ i1T) {
  int t = blockIdx.x * 256 + threadIdx.x;
  if (t < 128 * 64) {  // [128 h][64 f] -> [64 f][128 h]
    int h = t / 64, f = t % 64;
    r0T[f * 128 + h] = r0[t];
    i0T[f * 128 + h] = i0[t];
  }
  if (t < 128 * 128) {  // [128 h][128 f] -> [128 f][128 h]
    int h = t / 128, f = t % 128;
    r1T[f * 128 + h] = r1[t];
    i1T[f * 128 + h] = i1[t];
  }
}

// ---------------- pack re/im into interleaved rows ----------------

__global__ __launch_bounds__(256) void pack_kernel(const float* __restrict__ re,
                                                   const float* __restrict__ im,
                                                   float2* __restrict__ X,
                                                   int total) {  // total = N*64
  int i = blockIdx.x * 256 + threadIdx.x;
  if (i < total) X[i] = make_float2(re[i], im[i]);
}

// ---------------- complex propagation: wave = node, lane = float2 ------------
// X rows are [re0,im0,...] (128 floats = 64 float2). Lane l owns feature l.
// beg/end forced to SGPRs -> col_s/ws stream via s_load (scalar path); each
// edge is one 512B wave gather with 8 in flight.

__global__ __launch_bounds__(256) void prop_kernel(
    const float* __restrict__ X, float* __restrict__ Y,
    const int* __restrict__ offs, const int* __restrict__ col_s,
    const float2* __restrict__ ws, int n) {
  int wave = (int)((blockIdx.x * (size_t)blockDim.x + threadIdx.x) >> 6);
  int lane = threadIdx.x & 63;
  if (wave >= n) return;
  int beg = __builtin_amdgcn_readfirstlane(offs[wave]);
  int end = __builtin_amdgcn_readfirstlane(offs[wave + 1]);
  const float2* Xl = (const float2*)X + lane;
  float2 acc = make_float2(0.f, 0.f);
  int j = beg;
  for (; j + 8 <= end; j += 8) {
    int c[8];
#pragma unroll
    for (int k = 0; k < 8; ++k) c[k] = col_s[j + k];  // s_load_dwordx8
    float2 x[8];
#pragma unroll
    for (int k = 0; k < 8; ++k) x[k] = Xl[(size_t)c[k] * 64];  // 8 gathers
#pragma unroll
    for (int k = 0; k < 8; ++k) {
      float2 w = ws[j + k];  // s_load
      acc.x += w.x * x[k].x - w.y * x[k].y;
      acc.y += w.y * x[k].x + w.x * x[k].y;
    }
  }
  int rem = end - j;
  if (rem > 0) {
    int c[8];
#pragma unroll
    for (int k = 0; k < 8; ++k)
      if (k < rem) c[k] = col_s[j + k];
    float2 x[8];
#pragma unroll
    for (int k = 0; k < 8; ++k)
      if (k < rem) x[k] = Xl[(size_t)c[k] * 64];
#pragma unroll
    for (int k = 0; k < 8; ++k)
      if (k < rem) {
        float2 w = ws[j + k];
        acc.x += w.x * x[k].x - w.y * x[k].y;
        acc.y += w.y * x[k].x + w.x * x[k].y;
      }
  }
  ((float2*)Y)[(size_t)wave * 64 + lane] = acc;
}

// ---------------- attention pooling -> PT [128 f][NST nodes] ----------------

__device__ __forceinline__ float wave_sum(float v) {
#pragma unroll
  for (int d = 32; d > 0; d >>= 1) v += __shfl_xor(v, d, 64);
  return v;
}

__global__ __launch_bounds__(256) void pool_kernel(
    const float* __restrict__ R0f, const float* __restrict__ I0f,
    const float* __restrict__ X1, const float* __restrict__ X2,
    const float* __restrict__ X3, const float* __restrict__ rattw,
    const float* __restrict__ rattb, const float* __restrict__ iattw,
    const float* __restrict__ iattb, float* __restrict__ PT, int n) {
  __shared__ float pt[128 * 65];  // 33.3 KB, [f-row][node-col], stride 65
  int wid = threadIdx.x >> 6, lane = threadIdx.x & 63;
  int nb = blockIdx.x * 64;
  float aw = rattw[lane], bw = iattw[lane];
  float rb0 = rattb[0], ib0 = iattb[0];
  for (int k = 0; k < 16; ++k) {
    int ln = wid * 16 + k;
    int nc = min(nb + ln, n - 1);
    float r0 = R0f[(size_t)nc * 64 + lane];
    float q0 = I0f[(size_t)nc * 64 + lane];
    size_t base = (size_t)nc * 128 + 2 * lane;
    float2 v1 = *(const float2*)&X1[base];
    float2 v2 = *(const float2*)&X2[base];
    float2 v3 = *(const float2*)&X3[base];
    float ra0 = wave_sum(r0 * aw) + rb0;
    float ra1 = wave_sum(v1.x * aw) + rb0;
    float ra2 = wave_sum(v2.x * aw) + rb0;
    float ra3 = wave_sum(v3.x * aw) + rb0;
    float ia0 = wave_sum(q0 * bw) + ib0;
    float ia1 = wave_sum(v1.y * bw) + ib0;
    float ia2 = wave_sum(v2.y * bw) + ib0;
    float ia3 = wave_sum(v3.y * bw) + ib0;
    float s0 = 1.f / (1.f + __expf(-ra0));
    float s1 = 1.f / (1.f + __expf(-ra1));
    float s2 = 1.f / (1.f + __expf(-ra2));
    float s3 = 1.f / (1.f + __expf(-ra3));
    float t0 = 1.f / (1.f + __expf(-ia0));
    float t1 = 1.f / (1.f + __expf(-ia1));
    float t2 = 1.f / (1.f + __expf(-ia2));
    float t3 = 1.f / (1.f + __expf(-ia3));
    float mR = fmaxf(fmaxf(s0, s1), fmaxf(s2, s3));
    float e0 = __expf(s0 - mR), e1 = __expf(s1 - mR), e2 = __expf(s2 - mR),
          e3 = __expf(s3 - mR);
    float invR = 1.f / (e0 + e1 + e2 + e3);
    float mI = fmaxf(fmaxf(t0, t1), fmaxf(t2, t3));
    float g0 = __expf(t0 - mI), g1 = __expf(t1 - mI), g2 = __expf(t2 - mI),
          g3 = __expf(t3 - mI);
    float invI = 1.f / (g0 + g1 + g2 + g3);
    float pr = (r0 * e0 + v1.x * e1 + v2.x * e2 + v3.x * e3) * invR;
    float pi = (q0 * g0 + v1.y * g1 + v2.y * g2 + v3.y * g3) * invI;
    pt[lane * 65 + ln] = pr;
    pt[(64 + lane) * 65 + ln] = pi;
  }
  __syncthreads();
  int c = threadIdx.x & 63, fr = threadIdx.x >> 6;
  for (int r = 0; r < 32; ++r) {
    int f = fr * 32 + r;
    int nd = nb + c;
    if (nd < n) PT[(size_t)f * NST + nd] = pt[f * 65 + c];
  }
}

// ---------------- fused MLP: per-node LDS rows, float4 staging ----------------
// zt is [64 node][132] floats (528B stride, 33-word -> even bank coverage for
// b128). Thread (wid,lane): node=lane, h slice [wid*16, wid*16+16). Re and im
// GEMMs share the tile sequentially (they couple only via thread-local masks).

__global__ __launch_bounds__(512, 8) void mlp_kernel(
    const float* __restrict__ PT, const float* __restrict__ r0T,
    const float* __restrict__ r0b, const float* __restrict__ i0T,
    const float* __restrict__ i0b, const float* __restrict__ r1T,
    const float* __restrict__ r1b, const float* __restrict__ i1T,
    const float* __restrict__ i1b, const float* __restrict__ ow,
    const float* __restrict__ ob, float* __restrict__ out, int n) {
  __shared__ float zt[64 * 132];  // 33.8 KB
  int lane = threadIdx.x & 63;
  int wid = threadIdx.x >> 6;  // 0..7
  int h0 = __builtin_amdgcn_readfirstlane(wid * 16);
  int nb = blockIdx.x * 64;
  int node = min(nb + lane, n - 1);  // tail lanes duplicate node n-1 (benign)
  float* zrow = &zt[lane * 132];

  // ---- layer 0: zr,zi for h in [h0,h0+16) ----
  float zr[16], zi[16];
#pragma unroll
  for (int j = 0; j < 16; ++j) {
    zr[j] = r0b[h0 + j];
    zi[j] = i0b[h0 + j];
  }
#pragma unroll 2
  for (int f = 0; f < 64; ++f) {
    float ar = PT[(size_t)f * NST + node];
    float ai = PT[(size_t)(64 + f) * NST + node];
    const float* wr = &r0T[f * 128 + h0];
    const float* wi = &i0T[f * 128 + h0];
#pragma unroll
    for (int j = 0; j < 16; ++j) {
      zr[j] += ar * wr[j];
      zi[j] += ai * wi[j];
    }
  }
#pragma unroll
  for (int j = 0; j < 16; ++j) {
    float m = (zr[j] >= 0.f) ? 1.f : 0.f;
    zr[j] *= m;
    zi[j] *= m;
  }

  // ---- layer 1, re pass ----
#pragma unroll
  for (int j4 = 0; j4 < 4; ++j4)
    *(float4*)&zrow[h0 + 4 * j4] = make_float4(zr[4 * j4], zr[4 * j4 + 1],
                                               zr[4 * j4 + 2], zr[4 * j4 + 3]);
  __syncthreads();
  float yr[16];
#pragma unroll
  for (int j = 0; j < 16; ++j) yr[j] = r1b[h0 + j];
#pragma unroll 2
  for (int f4 = 0; f4 < 32; ++f4) {
    float4 a4 = *(const float4*)&zrow[4 * f4];
    const float* w0 = &r1T[(4 * f4) * 128 + h0];
    const float* w1 = &r1T[(4 * f4 + 1) * 128 + h0];
    const float* w2 = &r1T[(4 * f4 + 2) * 128 + h0];
    const float* w3 = &r1T[(4 * f4 + 3) * 128 + h0];
#pragma unroll
    for (int j = 0; j < 16; ++j)
      yr[j] += a4.x * w0[j] + a4.y * w1[j] + a4.z * w2[j] + a4.w * w3[j];
  }
  __syncthreads();

  // ---- layer 1, im pass ----
#pragma unroll
  for (int j4 = 0; j4 < 4; ++j4)
    *(float4*)&zrow[h0 + 4 * j4] = make_float4(zi[4 * j4], zi[4 * j4 + 1],
                                               zi[4 * j4 + 2], zi[4 * j4 + 3]);
  __syncthreads();
  float yi[16];
#pragma unroll
  for (int j = 0; j < 16; ++j) yi[j] = i1b[h0 + j];
#pragma unroll 2
  for (int f4 = 0; f4 < 32; ++f4) {
    float4 a4 = *(const float4*)&zrow[4 * f4];
    const float* w0 = &i1T[(4 * f4) * 128 + h0];
    const float* w1 = &i1T[(4 * f4 + 1) * 128 + h0];
    const float* w2 = &i1T[(4 * f4 + 2) * 128 + h0];
    const float* w3 = &i1T[(4 * f4 + 3) * 128 + h0];
#pragma unroll
    for (int j = 0; j < 16; ++j)
      yi[j] += a4.x * w0[j] + a4.y * w1[j] + a4.z * w2[j] + a4.w * w3[j];
  }
#pragma unroll
  for (int j = 0; j < 16; ++j) {
    float m = (yr[j] >= 0.f) ? 1.f : 0.f;
    yr[j] *= m;
    yi[j] *= m;
  }
  __syncthreads();

  // ---- output layer: wave w owns o = 4w..4w+3 ----
  int o0 = __builtin_amdgcn_readfirstlane(wid * 4);
  float os[4] = {0.f, 0.f, 0.f, 0.f};
#pragma unroll
  for (int j4 = 0; j4 < 4; ++j4)
    *(float4*)&zrow[h0 + 4 * j4] = make_float4(yr[4 * j4], yr[4 * j4 + 1],
                                               yr[4 * j4 + 2], yr[4 * j4 + 3]);
  __syncthreads();
#pragma unroll 2
  for (int f4 = 0; f4 < 32; ++f4) {
    float4 v = *(const float4*)&zrow[4 * f4];
#pragma unroll
    for (int oo = 0; oo < 4; ++oo) {
      const float* w = &ow[(o0 + oo) * 256 + 4 * f4];
      os[oo] += v.x * w[0] + v.y * w[1] + v.z * w[2] + v.w * w[3];
    }
  }
  __syncthreads();
#pragma unroll
  for (int j4 = 0; j4 < 4; ++j4)
    *(float4*)&zrow[h0 + 4 * j4] = make_float4(yi[4 * j4], yi[4 * j4 + 1],
                                               yi[4 * j4 + 2], yi[4 * j4 + 3]);
  __syncthreads();
#pragma unroll 2
  for (int f4 = 0; f4 < 32; ++f4) {
    float4 v = *(const float4*)&zrow[4 * f4];
#pragma unroll
    for (int oo = 0; oo < 4; ++oo) {
      const float* w = &ow[(o0 + oo) * 256 + 128 + 4 * f4];
      os[oo] += v.x * w[0] + v.y * w[1] + v.z * w[2] + v.w * w[3];
    }
  }
#pragma unroll
  for (int oo = 0; oo < 4; ++oo)
    out[(size_t)node * 32 + o0 + oo] = os[oo] + ob[o0 + oo];
}

// ---------------- launch ----------------

extern "C" void kernel_launch(void* const* d_in, const int* in_sizes, int n_in,
                              void* d_out, int out_size, void* d_ws,
                              size_t ws_size, hipStream_t stream) {
  const float* realf = (const float*)d_in[0];
  const float* imagf = (const float*)d_in[1];
  const float* ent = (const float*)d_in[2];
  const float* ccf = (const float*)d_in[3];
  const float* wsym = (const float*)d_in[4];
  const float* q = (const float*)d_in[5];
  const float* encw = (const float*)d_in[6];
  const float* encb = (const float*)d_in[7];
  const float* rattw = (const float*)d_in[8];
  const float* rattb = (const float*)d_in[9];
  const float* iattw = (const float*)d_in[10];
  const float* iattb = (const float*)d_in[11];
  const float* r0w = (const float*)d_in[12];
  const float* r0b = (const float*)d_in[13];
  const float* r1w = (const float*)d_in[14];
  const float* r1b = (const float*)d_in[15];
  const float* i0w = (const float*)d_in[16];
  const float* i0b = (const float*)d_in[17];
  const float* i1w = (const float*)d_in[18];
  const float* i1b = (const float*)d_in[19];
  const float* ow = (const float*)d_in[20];
  const float* ob = (const float*)d_in[21];
  const int* row = (const int*)d_in[22];
  const int* col = (const int*)d_in[23];
  float* out = (float*)d_out;

  char* p = (char*)d_ws;
  auto alloc = [&](size_t bytes) -> void* {
    void* r = (void*)p;
    p += (bytes + 255) & ~(size_t)255;
    return r;
  };
  int* cnt = (int*)alloc(N_NODES * sizeof(int));
  int* offs = (int*)alloc((N_NODES + 1) * sizeof(int));
  int* bsum = (int*)alloc(SA_BLOCKS * sizeof(int));
  int* boff = (int*)alloc(SA_BLOCKS * sizeof(int));
  int* col_s = (int*)alloc(N_EDGES * sizeof(int));
  float2* ws2 = (float2*)alloc(N_EDGES * sizeof(float2));
  size_t NX = (size_t)N_NODES * 128 * sizeof(float);  // interleaved level
  float* X0 = (float*)alloc(NX);
  float* X1 = (float*)alloc(NX);
  float* X2 = (float*)alloc(NX);
  float* X3 = (float*)alloc(NX);
  float* PT = (float*)alloc((size_t)128 * NST * sizeof(float));
  float* r0T = (float*)alloc(64 * 128 * 4);
  float* i0T = (float*)alloc(64 * 128 * 4);
  float* r1T = (float*)alloc(128 * 128 * 4);
  float* i1T = (float*)alloc(128 * 128 * 4);

  hipMemsetAsync(cnt, 0, N_NODES * sizeof(int), stream);
  prep_weights<<<64, 256, 0, stream>>>(r0w, i0w, r1w, i1w, r0T, i0T, r1T, i1T);
  hist_kernel<<<(N_EDGES + 255) / 256, 256, 0, stream>>>(row, cnt, N_EDGES);
  scanA_kernel<<<SA_BLOCKS, 1024, 0, stream>>>(cnt, offs, bsum, N_NODES);
  scanB_kernel<<<1, 64, 0, stream>>>(bsum, boff, SA_BLOCKS);
  scanC_kernel<<<SA_BLOCKS, 1024, 0, stream>>>(offs, cnt, boff, N_NODES,
                                               N_EDGES);
  scatter_kernel<<<(N_EDGES + 255) / 256, 256, 0, stream>>>(
      row, col, ent, ccf, wsym, encw, encb, q, cnt, col_s, ws2, N_EDGES);
  pack_kernel<<<(N_NODES * 64 + 255) / 256, 256, 0, stream>>>(
      realf, imagf, (float2*)X0, N_NODES * 64);

  const int pgrid = (N_NODES + 3) / 4;  // 4 waves (nodes) per 256-thread block
  prop_kernel<<<pgrid, 256, 0, stream>>>(X0, X1, offs, col_s, ws2, N_NODES);
  prop_kernel<<<pgrid, 256, 0, stream>>>(X1, X2, offs, col_s, ws2, N_NODES);
  prop_kernel<<<pgrid, 256, 0, stream>>>(X2, X3, offs, col_s, ws2, N_NODES);

  const int hgrid = (N_NODES + 63) / 64;  // 64 nodes per block
  pool_kernel<<<hgrid, 256, 0, stream>>>(realf, imagf, X1, X2, X3, rattw,
                                         rattb, iattw, iattb, PT, N_NODES);
  mlp_kernel<<<hgrid, 512, 0, stream>>>(PT, r0T, r0b, i0T, i0b, r1T, r1b, i1T,
                                        i1b, ow, ob, out, N_NODES);
}

// Round 9
// 404.805 us; speedup vs baseline: 1.0506x; 1.0506x over previous
//
#include <hip/hip_runtime.h>

#define N_NODES 50000
#define N_EDGES 800000
#define FDIM 64
#define SA_BLOCKS ((N_NODES + 1023) / 1024)

// ---------------- edge weight + CSR construction ----------------

__global__ __launch_bounds__(256) void hist_kernel(const int* __restrict__ row,
                                                   int* __restrict__ cnt, int E) {
  int e = blockIdx.x * 256 + threadIdx.x;
  if (e < E) atomicAdd(&cnt[row[e]], 1);
}

// hierarchical scan: A) per-1024 block scan, B) scan block sums, C) apply
__global__ __launch_bounds__(1024) void scanA_kernel(const int* __restrict__ cnt,
                                                     int* __restrict__ offs,
                                                     int* __restrict__ bsum,
                                                     int n) {
  __shared__ int s[1024];
  int t = threadIdx.x;
  int i = blockIdx.x * 1024 + t;
  int v = (i < n) ? cnt[i] : 0;
  s[t] = v;
  __syncthreads();
  for (int d = 1; d < 1024; d <<= 1) {
    int add = (t >= d) ? s[t - d] : 0;
    __syncthreads();
    s[t] += add;
    __syncthreads();
  }
  if (i < n) offs[i] = s[t] - v;  // local exclusive
  if (t == 1023) bsum[blockIdx.x] = s[1023];
}

__global__ __launch_bounds__(64) void scanB_kernel(int* __restrict__ bsum,
                                                   int* __restrict__ boff,
                                                   int nb) {
  __shared__ int s[64];
  int t = threadIdx.x;
  int v = (t < nb) ? bsum[t] : 0;
  s[t] = v;
  __syncthreads();
  for (int d = 1; d < 64; d <<= 1) {
    int add = (t >= d) ? s[t - d] : 0;
    __syncthreads();
    s[t] += add;
    __syncthreads();
  }
  if (t < nb) boff[t] = s[t] - v;  // exclusive
}

__global__ __launch_bounds__(1024) void scanC_kernel(int* __restrict__ offs,
                                                     int* __restrict__ cursor,
                                                     const int* __restrict__ boff,
                                                     int n, int E) {
  int t = threadIdx.x;
  int i = blockIdx.x * 1024 + t;
  int bo = boff[blockIdx.x];
  if (i < n) {
    int o = offs[i] + bo;
    offs[i] = o;
    cursor[i] = o;
  }
  if (i == 0) offs[n] = E;
}

__global__ __launch_bounds__(256) void scatter_kernel(
    const int* __restrict__ row, const int* __restrict__ col,
    const float* __restrict__ ent, const float* __restrict__ ccf,
    const float* __restrict__ wsym, const float* __restrict__ encw,
    const float* __restrict__ encb, const float* __restrict__ q,
    int* __restrict__ cursor, int* __restrict__ col_s,
    float2* __restrict__ ws, int E) {
  int e = blockIdx.x * 256 + threadIdx.x;
  if (e >= E) return;
  float se = encw[0] * ent[e] + encw[1] * ccf[e] + encb[0];
  float ph = q[0] * se;
  float sw, cw;
  sincosf(ph, &sw, &cw);
  float w = wsym[e];
  int pos = atomicAdd(&cursor[row[e]], 1);
  col_s[pos] = col[e];
  ws[pos] = make_float2(w * cw, w * sw);
}

// ---------------- weight transpose prep ----------------

__global__ __launch_bounds__(256) void prep_weights(
    const float* __restrict__ r0, const float* __restrict__ i0,
    const float* __restrict__ r1, const float* __restrict__ i1,
    float* __restrict__ r0T, float* __restrict__ i0T, float* __restrict__ r1T,
    float* __restrict__ i1T) {
  int t = blockIdx.x * 256 + threadIdx.x;
  if (t < 128 * 64) {  // [128 h][64 f] -> [64 f][128 h]
    int h = t / 64, f = t % 64;
    r0T[f * 128 + h] = r0[t];
    i0T[f * 128 + h] = i0[t];
  }
  if (t < 128 * 128) {  // [128 h][128 f] -> [128 f][128 h]
    int h = t / 128, f = t % 128;
    r1T[f * 128 + h] = r1[t];
    i1T[f * 128 + h] = i1[t];
  }
}

// ---------------- pack re/im into interleaved rows ----------------

__global__ __launch_bounds__(256) void pack_kernel(const float* __restrict__ re,
                                                   const float* __restrict__ im,
                                                   float2* __restrict__ X,
                                                   int total) {  // total = N*64
  int i = blockIdx.x * 256 + threadIdx.x;
  if (i < total) X[i] = make_float2(re[i], im[i]);
}

// ---------------- complex propagation: wave = node, lane = (re,im) pair ------
// All f32 (fp16 gather failed accuracy: absmax 0.267 > 0.0578 in R8).
// beg/end via readfirstlane -> col_s/ws stream on the scalar path; each edge
// is one 512B wave gather, 8 in flight.

__global__ __launch_bounds__(256) void prop_kernel(
    const float* __restrict__ X, float* __restrict__ Y,
    const int* __restrict__ offs, const int* __restrict__ col_s,
    const float2* __restrict__ ws, int n) {
  int wave = (int)((blockIdx.x * (size_t)blockDim.x + threadIdx.x) >> 6);
  int lane = threadIdx.x & 63;
  if (wave >= n) return;
  int beg = __builtin_amdgcn_readfirstlane(offs[wave]);
  int end = __builtin_amdgcn_readfirstlane(offs[wave + 1]);
  const float2* Xl = (const float2*)X + lane;
  float2 acc = make_float2(0.f, 0.f);
  int j = beg;
  for (; j + 8 <= end; j += 8) {
    int c[8];
#pragma unroll
    for (int k = 0; k < 8; ++k) c[k] = col_s[j + k];  // s_load path
    float2 x[8];
#pragma unroll
    for (int k = 0; k < 8; ++k) x[k] = Xl[(size_t)c[k] * 64];
#pragma unroll
    for (int k = 0; k < 8; ++k) {
      float2 w = ws[j + k];
      acc.x += w.x * x[k].x - w.y * x[k].y;
      acc.y += w.y * x[k].x + w.x * x[k].y;
    }
  }
  int rem = end - j;
  if (rem > 0) {
    int c[8];
#pragma unroll
    for (int k = 0; k < 8; ++k)
      if (k < rem) c[k] = col_s[j + k];
    float2 x[8];
#pragma unroll
    for (int k = 0; k < 8; ++k)
      if (k < rem) x[k] = Xl[(size_t)c[k] * 64];
#pragma unroll
    for (int k = 0; k < 8; ++k)
      if (k < rem) {
        float2 w = ws[j + k];
        acc.x += w.x * x[k].x - w.y * x[k].y;
        acc.y += w.y * x[k].x + w.x * x[k].y;
      }
  }
  ((float2*)Y)[(size_t)wave * 64 + lane] = acc;
}

// ---------------- fused pooling + MLP + output ----------------
// 512 threads = 8 waves, 64 nodes per block. Phase P: wave wid pools nodes
// wid*8..wid*8+7 into the LDS tile buf[f*65+node] (the exact layout layer 0
// consumes). Then the same buffer is reused as the [64 node][132] z/y staging
// tile. Weights stream via s_load (wave-uniform h0/o0).

__device__ __forceinline__ float wave_sum(float v) {
#pragma unroll
  for (int d = 32; d > 0; d >>= 1) v += __shfl_xor(v, d, 64);
  return v;
}

__global__ __launch_bounds__(512, 8) void fused_head(
    const float* __restrict__ R0f, const float* __restrict__ I0f,
    const float* __restrict__ X1, const float* __restrict__ X2,
    const float* __restrict__ X3, const float* __restrict__ rattw,
    const float* __restrict__ rattb, const float* __restrict__ iattw,
    const float* __restrict__ iattb, const float* __restrict__ r0T,
    const float* __restrict__ r0b, const float* __restrict__ i0T,
    const float* __restrict__ i0b, const float* __restrict__ r1T,
    const float* __restrict__ r1b, const float* __restrict__ i1T,
    const float* __restrict__ i1b, const float* __restrict__ ow,
    const float* __restrict__ ob, float* __restrict__ out, int n) {
  __shared__ float buf[8448];  // 33.8 KB: pt [128][65] then zt [64][132]
  int lane = threadIdx.x & 63;
  int wid = threadIdx.x >> 6;  // 0..7
  int nb = blockIdx.x * 64;

  // ---- phase P: attention pooling into buf[f*65 + node] ----
  {
    float aw = rattw[lane], bw = iattw[lane];
    float rb0 = rattb[0], ib0 = iattb[0];
    for (int k = 0; k < 8; ++k) {
      int ln = wid * 8 + k;
      int nc = min(nb + ln, n - 1);
      float r0 = R0f[(size_t)nc * 64 + lane];
      float q0 = I0f[(size_t)nc * 64 + lane];
      size_t base = (size_t)nc * 128 + 2 * lane;
      float2 v1 = *(const float2*)&X1[base];
      float2 v2 = *(const float2*)&X2[base];
      float2 v3 = *(const float2*)&X3[base];
      float ra0 = wave_sum(r0 * aw) + rb0;
      float ra1 = wave_sum(v1.x * aw) + rb0;
      float ra2 = wave_sum(v2.x * aw) + rb0;
      float ra3 = wave_sum(v3.x * aw) + rb0;
      float ia0 = wave_sum(q0 * bw) + ib0;
      float ia1 = wave_sum(v1.y * bw) + ib0;
      float ia2 = wave_sum(v2.y * bw) + ib0;
      float ia3 = wave_sum(v3.y * bw) + ib0;
      float s0 = 1.f / (1.f + __expf(-ra0));
      float s1 = 1.f / (1.f + __expf(-ra1));
      float s2 = 1.f / (1.f + __expf(-ra2));
      float s3 = 1.f / (1.f + __expf(-ra3));
      float t0 = 1.f / (1.f + __expf(-ia0));
      float t1 = 1.f / (1.f + __expf(-ia1));
      float t2 = 1.f / (1.f + __expf(-ia2));
      float t3 = 1.f / (1.f + __expf(-ia3));
      float mR = fmaxf(fmaxf(s0, s1), fmaxf(s2, s3));
      float e0 = __expf(s0 - mR), e1 = __expf(s1 - mR), e2 = __expf(s2 - mR),
            e3 = __expf(s3 - mR);
      float invR = 1.f / (e0 + e1 + e2 + e3);
      float mI = fmaxf(fmaxf(t0, t1), fmaxf(t2, t3));
      float g0 = __expf(t0 - mI), g1 = __expf(t1 - mI), g2 = __expf(t2 - mI),
            g3 = __expf(t3 - mI);
      float invI = 1.f / (g0 + g1 + g2 + g3);
      float pr = (r0 * e0 + v1.x * e1 + v2.x * e2 + v3.x * e3) * invR;
      float pi = (q0 * g0 + v1.y * g1 + v2.y * g2 + v3.y * g3) * invI;
      buf[lane * 65 + ln] = pr;
      buf[(64 + lane) * 65 + ln] = pi;
    }
  }
  __syncthreads();

  // ---- layer 0: zr,zi for h in [h0,h0+16), activations from LDS ----
  int h0 = __builtin_amdgcn_readfirstlane(wid * 16);
  float zr[16], zi[16];
#pragma unroll
  for (int j = 0; j < 16; ++j) {
    zr[j] = r0b[h0 + j];
    zi[j] = i0b[h0 + j];
  }
#pragma unroll 2
  for (int f = 0; f < 64; ++f) {
    float ar = buf[f * 65 + lane];
    float ai = buf[(64 + f) * 65 + lane];
    const float* wr = &r0T[f * 128 + h0];
    const float* wi = &i0T[f * 128 + h0];
#pragma unroll
    for (int j = 0; j < 16; ++j) {
      zr[j] += ar * wr[j];
      zi[j] += ai * wi[j];
    }
  }
#pragma unroll
  for (int j = 0; j < 16; ++j) {
    float m = (zr[j] >= 0.f) ? 1.f : 0.f;
    zr[j] *= m;
    zi[j] *= m;
  }
  __syncthreads();  // all pt reads done; reuse buf as [64][132] staging

  float* zrow = &buf[lane * 132];

  // ---- layer 1, re pass ----
#pragma unroll
  for (int j4 = 0; j4 < 4; ++j4)
    *(float4*)&zrow[h0 + 4 * j4] = make_float4(zr[4 * j4], zr[4 * j4 + 1],
                                               zr[4 * j4 + 2], zr[4 * j4 + 3]);
  __syncthreads();
  float yr[16];
#pragma unroll
  for (int j = 0; j < 16; ++j) yr[j] = r1b[h0 + j];
#pragma unroll 2
  for (int f4 = 0; f4 < 32; ++f4) {
    float4 a4 = *(const float4*)&zrow[4 * f4];
    const float* w0 = &r1T[(4 * f4) * 128 + h0];
    const float* w1 = &r1T[(4 * f4 + 1) * 128 + h0];
    const float* w2 = &r1T[(4 * f4 + 2) * 128 + h0];
    const float* w3 = &r1T[(4 * f4 + 3) * 128 + h0];
#pragma unroll
    for (int j = 0; j < 16; ++j)
      yr[j] += a4.x * w0[j] + a4.y * w1[j] + a4.z * w2[j] + a4.w * w3[j];
  }
  __syncthreads();

  // ---- layer 1, im pass ----
#pragma unroll
  for (int j4 = 0; j4 < 4; ++j4)
    *(float4*)&zrow[h0 + 4 * j4] = make_float4(zi[4 * j4], zi[4 * j4 + 1],
                                               zi[4 * j4 + 2], zi[4 * j4 + 3]);
  __syncthreads();
  float yi[16];
#pragma unroll
  for (int j = 0; j < 16; ++j) yi[j] = i1b[h0 + j];
#pragma unroll 2
  for (int f4 = 0; f4 < 32; ++f4) {
    float4 a4 = *(const float4*)&zrow[4 * f4];
    const float* w0 = &i1T[(4 * f4) * 128 + h0];
    const float* w1 = &i1T[(4 * f4 + 1) * 128 + h0];
    const float* w2 = &i1T[(4 * f4 + 2) * 128 + h0];
    const float* w3 = &i1T[(4 * f4 + 3) * 128 + h0];
#pragma unroll
    for (int j = 0; j < 16; ++j)
      yi[j] += a4.x * w0[j] + a4.y * w1[j] + a4.z * w2[j] + a4.w * w3[j];
  }
#pragma unroll
  for (int j = 0; j < 16; ++j) {
    float m = (yr[j] >= 0.f) ? 1.f : 0.f;
    yr[j] *= m;
    yi[j] *= m;
  }
  __syncthreads();

  // ---- output layer: wave w owns o = 4w..4w+3 ----
  int node = min(nb + lane, n - 1);
  int o0 = __builtin_amdgcn_readfirstlane(wid * 4);
  float os[4] = {0.f, 0.f, 0.f, 0.f};
#pragma unroll
  for (int j4 = 0; j4 < 4; ++j4)
    *(float4*)&zrow[h0 + 4 * j4] = make_float4(yr[4 * j4], yr[4 * j4 + 1],
                                               yr[4 * j4 + 2], yr[4 * j4 + 3]);
  __syncthreads();
#pragma unroll 2
  for (int f4 = 0; f4 < 32; ++f4) {
    float4 v = *(const float4*)&zrow[4 * f4];
#pragma unroll
    for (int oo = 0; oo < 4; ++oo) {
      const float* w = &ow[(o0 + oo) * 256 + 4 * f4];
      os[oo] += v.x * w[0] + v.y * w[1] + v.z * w[2] + v.w * w[3];
    }
  }
  __syncthreads();
#pragma unroll
  for (int j4 = 0; j4 < 4; ++j4)
    *(float4*)&zrow[h0 + 4 * j4] = make_float4(yi[4 * j4], yi[4 * j4 + 1],
                                               yi[4 * j4 + 2], yi[4 * j4 + 3]);
  __syncthreads();
#pragma unroll 2
  for (int f4 = 0; f4 < 32; ++f4) {
    float4 v = *(const float4*)&zrow[4 * f4];
#pragma unroll
    for (int oo = 0; oo < 4; ++oo) {
      const float* w = &ow[(o0 + oo) * 256 + 128 + 4 * f4];
      os[oo] += v.x * w[0] + v.y * w[1] + v.z * w[2] + v.w * w[3];
    }
  }
#pragma unroll
  for (int oo = 0; oo < 4; ++oo)
    out[(size_t)node * 32 + o0 + oo] = os[oo] + ob[o0 + oo];
}

// ---------------- launch ----------------

extern "C" void kernel_launch(void* const* d_in, const int* in_sizes, int n_in,
                              void* d_out, int out_size, void* d_ws,
                              size_t ws_size, hipStream_t stream) {
  const float* realf = (const float*)d_in[0];
  const float* imagf = (const float*)d_in[1];
  const float* ent = (const float*)d_in[2];
  const float* ccf = (const float*)d_in[3];
  const float* wsym = (const float*)d_in[4];
  const float* q = (const float*)d_in[5];
  const float* encw = (const float*)d_in[6];
  const float* encb = (const float*)d_in[7];
  const float* rattw = (const float*)d_in[8];
  const float* rattb = (const float*)d_in[9];
  const float* iattw = (const float*)d_in[10];
  const float* iattb = (const float*)d_in[11];
  const float* r0w = (const float*)d_in[12];
  const float* r0b = (const float*)d_in[13];
  const float* r1w = (const float*)d_in[14];
  const float* r1b = (const float*)d_in[15];
  const float* i0w = (const float*)d_in[16];
  const float* i0b = (const float*)d_in[17];
  const float* i1w = (const float*)d_in[18];
  const float* i1b = (const float*)d_in[19];
  const float* ow = (const float*)d_in[20];
  const float* ob = (const float*)d_in[21];
  const int* row = (const int*)d_in[22];
  const int* col = (const int*)d_in[23];
  float* out = (float*)d_out;

  char* p = (char*)d_ws;
  auto alloc = [&](size_t bytes) -> void* {
    void* r = (void*)p;
    p += (bytes + 255) & ~(size_t)255;
    return r;
  };
  int* cnt = (int*)alloc(N_NODES * sizeof(int));
  int* offs = (int*)alloc((N_NODES + 1) * sizeof(int));
  int* bsum = (int*)alloc(SA_BLOCKS * sizeof(int));
  int* boff = (int*)alloc(SA_BLOCKS * sizeof(int));
  int* col_s = (int*)alloc(N_EDGES * sizeof(int));
  float2* ws2 = (float2*)alloc(N_EDGES * sizeof(float2));
  size_t NX = (size_t)N_NODES * 128 * sizeof(float);  // interleaved level
  float* X0 = (float*)alloc(NX);
  float* X1 = (float*)alloc(NX);
  float* X2 = (float*)alloc(NX);
  float* X3 = (float*)alloc(NX);
  float* r0T = (float*)alloc(64 * 128 * 4);
  float* i0T = (float*)alloc(64 * 128 * 4);
  float* r1T = (float*)alloc(128 * 128 * 4);
  float* i1T = (float*)alloc(128 * 128 * 4);

  hipMemsetAsync(cnt, 0, N_NODES * sizeof(int), stream);
  prep_weights<<<64, 256, 0, stream>>>(r0w, i0w, r1w, i1w, r0T, i0T, r1T, i1T);
  hist_kernel<<<(N_EDGES + 255) / 256, 256, 0, stream>>>(row, cnt, N_EDGES);
  scanA_kernel<<<SA_BLOCKS, 1024, 0, stream>>>(cnt, offs, bsum, N_NODES);
  scanB_kernel<<<1, 64, 0, stream>>>(bsum, boff, SA_BLOCKS);
  scanC_kernel<<<SA_BLOCKS, 1024, 0, stream>>>(offs, cnt, boff, N_NODES,
                                               N_EDGES);
  scatter_kernel<<<(N_EDGES + 255) / 256, 256, 0, stream>>>(
      row, col, ent, ccf, wsym, encw, encb, q, cnt, col_s, ws2, N_EDGES);
  pack_kernel<<<(N_NODES * 64 + 255) / 256, 256, 0, stream>>>(
      realf, imagf, (float2*)X0, N_NODES * 64);

  const int pgrid = (N_NODES + 3) / 4;  // 4 waves (nodes) per 256-thread block
  prop_kernel<<<pgrid, 256, 0, stream>>>(X0, X1, offs, col_s, ws2, N_NODES);
  prop_kernel<<<pgrid, 256, 0, stream>>>(X1, X2, offs, col_s, ws2, N_NODES);
  prop_kernel<<<pgrid, 256, 0, stream>>>(X2, X3, offs, col_s, ws2, N_NODES);

  const int hgrid = (N_NODES + 63) / 64;  // 64 nodes per block
  fused_head<<<hgrid, 512, 0, stream>>>(realf, imagf, X1, X2, X3, rattw, rattb,
                                        iattw, iattb, r0T, r0b, i0T, i0b, r1T,
                                        r1b, i1T, i1b, ow, ob, out, N_NODES);
}